// Round 6
// baseline (1343.630 us; speedup 1.0000x reference)
//
#include <hip/hip_runtime.h>
#include <math.h>

#define NKER 125

// ---------------- zero: one kernel zeroes all layers' A + deg regions ----------------
__global__ __launch_bounds__(256) void zero_kernel(float4* __restrict__ p, int n4) {
  int stride = gridDim.x * 256;
  for (int i = blockIdx.x * 256 + threadIdx.x; i < n4; i += stride)
    p[i] = make_float4(0.0f, 0.0f, 0.0f, 0.0f);
}

// ---------------- scatter: A[dst*KS + kidx*Cin + i] += wprod * x[src,ci]; deg[dst] += 1 ----------------
__global__ __launch_bounds__(256) void scatter_kernel(
    const int* __restrict__ ei, const float* __restrict__ ea,
    const float* __restrict__ x, float* __restrict__ A,
    float* __restrict__ deg, int E, int cinShift, int KS) {
  int tid = blockIdx.x * 256 + threadIdx.x;
  int Cin = 1 << cinShift;
  if (tid >= (E << cinShift)) return;
  int e = tid >> cinShift;
  int i = tid & (Cin - 1);
  int src = ei[e];
  int dst = ei[E + e];
  float xv = x[((size_t)src << cinShift) + i];
  float w[3][2];
  int k0[3];
#pragma unroll
  for (int d = 0; d < 3; d++) {
    float p = ea[e * 3 + d] * 4.0f;
    float kf = fminf(fmaxf(floorf(p), 0.0f), 3.0f);
    float f = p - kf;
    k0[d] = (int)kf;
    w[d][0] = 1.0f - f;
    w[d][1] = f;
  }
  float* Arow = A + (size_t)dst * KS + i;
#pragma unroll
  for (int c = 0; c < 8; c++) {
    int b0 = c & 1, b1 = (c >> 1) & 1, b2 = (c >> 2) & 1;
    float wp = w[0][b0] * w[1][b1] * w[2][b2];
    int kidx = (k0[0] + b0) + 5 * (k0[1] + b1) + 25 * (k0[2] + b2);
    atomicAdd(&Arow[kidx << cinShift], wp * xv);
  }
  if (i == 0) atomicAdd(&deg[dst], 1.0f);
}

// ---------------- GEMM v3: register-tiled 4x4, float4 staging, partials out ----------------
template <int BM, int COUT, int NT>
__global__ __launch_bounds__(NT) void gemm3_kernel(
    const float* __restrict__ A, const float* __restrict__ W,
    float* __restrict__ gpart, int M, int Kdim, int KS, int ktiles) {
  const int BK = 32;
  __shared__ float At[BK][BM + 4];
  __shared__ float Wl[BK][COUT];
  const int TC = COUT / 4;
  int tid = threadIdx.x;
  int tc = tid % TC;
  int tr = tid / TC;
  int m0 = blockIdx.x * BM;
  int kbeg = blockIdx.y * ktiles * BK;
  int kend = min(KS, kbeg + ktiles * BK);
  float ar[4][4];
#pragma unroll
  for (int i = 0; i < 4; i++)
#pragma unroll
    for (int j = 0; j < 4; j++) ar[i][j] = 0.0f;

  for (int k0 = kbeg; k0 < kend; k0 += BK) {
    for (int t = tid; t < BM * (BK / 4); t += NT) {
      int c4 = t % (BK / 4), r = t / (BK / 4);
      int m = m0 + r;
      float4 v = make_float4(0.0f, 0.0f, 0.0f, 0.0f);
      if (m < M) v = *(const float4*)&A[(size_t)m * KS + k0 + c4 * 4];
      At[c4 * 4 + 0][r] = v.x; At[c4 * 4 + 1][r] = v.y;
      At[c4 * 4 + 2][r] = v.z; At[c4 * 4 + 3][r] = v.w;
    }
    int kleft = Kdim - k0;
    if (kleft >= BK) {
      for (int t = tid; t < BK * COUT / 4; t += NT)
        ((float4*)&Wl[0][0])[t] = ((const float4*)&W[(size_t)k0 * COUT])[t];
    } else {
      for (int t = tid; t < BK * COUT; t += NT) {
        int kk = t / COUT, o = t % COUT;
        Wl[kk][o] = (kk < kleft) ? W[(size_t)(k0 + kk) * COUT + o] : 0.0f;
      }
    }
    __syncthreads();
#pragma unroll
    for (int kk = 0; kk < BK; kk++) {
      float4 a = *(const float4*)&At[kk][tr * 4];
      float4 w = *(const float4*)&Wl[kk][tc * 4];
      float av[4] = {a.x, a.y, a.z, a.w};
      float wv[4] = {w.x, w.y, w.z, w.w};
#pragma unroll
      for (int i = 0; i < 4; i++)
#pragma unroll
        for (int j = 0; j < 4; j++)
          ar[i][j] = fmaf(av[i], wv[j], ar[i][j]);
    }
    __syncthreads();
  }
  float* gp = gpart + ((size_t)blockIdx.y * M) * COUT + tc * 4;
#pragma unroll
  for (int i = 0; i < 4; i++) {
    int m = m0 + tr * 4 + i;
    if (m < M)
      *(float4*)(gp + (size_t)m * COUT) =
          make_float4(ar[i][0], ar[i][1], ar[i][2], ar[i][3]);
  }
}

// ---------------- elu helper ----------------
__device__ __forceinline__ float elu1(float v) { return v > 0.0f ? v : expm1f(v); }

// ---------------- pool v6: epilogue fused into LDS staging; OPT outputs per thread ----------------
template <int COUT, int OPT>
__global__ __launch_bounds__(256) void pool6_kernel(
    const float* __restrict__ P, const float* __restrict__ gpart,
    const float* __restrict__ deg, const float* __restrict__ x,
    const float* __restrict__ R, const float* __restrict__ bias,
    float* __restrict__ partial, int Nsrc, int Nnext, int Cin, int kchunks,
    int chunk, int items) {
  extern __shared__ float hs[];
  int c = blockIdx.y;
  int n0 = c * chunk;
  int n1 = min(Nsrc, n0 + chunk);
  int len = n1 - n0;
  // staging with fused epilogue: hs[nl][o] = elu(sum_k gpart/deg + x@R + b)
  size_t gstride = (size_t)Nsrc * COUT;
  for (int t = threadIdx.x; t < len * (COUT / 4); t += 256) {
    int nl = t / (COUT / 4), o4 = t % (COUT / 4);
    int n = n0 + nl;
    const float* gp = &gpart[(size_t)n * COUT + o4 * 4];
    float4 s = make_float4(0.0f, 0.0f, 0.0f, 0.0f);
    for (int k = 0; k < kchunks; k++) {
      float4 v = *(const float4*)(gp + (size_t)k * gstride);
      s.x += v.x; s.y += v.y; s.z += v.z; s.w += v.w;
    }
    float invd = 1.0f / fmaxf(deg[n], 1.0f);
    float4 r = *(const float4*)&bias[o4 * 4];
    const float* xr = &x[(size_t)n * Cin];
    for (int i = 0; i < Cin; i++) {
      float xv = xr[i];
      float4 Rv = *(const float4*)&R[(size_t)i * COUT + o4 * 4];
      r.x = fmaf(xv, Rv.x, r.x); r.y = fmaf(xv, Rv.y, r.y);
      r.z = fmaf(xv, Rv.z, r.z); r.w = fmaf(xv, Rv.w, r.w);
    }
    float4 v;
    v.x = elu1(fmaf(s.x, invd, r.x) + 0.0f);
    v.y = elu1(fmaf(s.y, invd, r.y) + 0.0f);
    v.z = elu1(fmaf(s.z, invd, r.z) + 0.0f);
    v.w = elu1(fmaf(s.w, invd, r.w) + 0.0f);
    ((float4*)hs)[t] = v;
  }
  __syncthreads();
  int item = blockIdx.x * 256 + threadIdx.x;
  if (item >= items) return;
  int nj4 = Nnext >> 2;
  int j0 = (item % nj4) << 2;
  int o0 = (item / nj4) * OPT;
  float ac[4][OPT];
#pragma unroll
  for (int a = 0; a < 4; a++)
#pragma unroll
    for (int b = 0; b < OPT; b++) ac[a][b] = 0.0f;
  const float* Pb = P + j0;
  int n = 0;
  for (; n + 8 <= len; n += 8) {
    float4 p[8];
#pragma unroll
    for (int u = 0; u < 8; u++)
      p[u] = *(const float4*)&Pb[(size_t)(n0 + n + u) * Nnext];
#pragma unroll
    for (int u = 0; u < 8; u++) {
      const float4* hr = (const float4*)&hs[(n + u) * COUT + o0];
      float pj[4] = {p[u].x, p[u].y, p[u].z, p[u].w};
#pragma unroll
      for (int q = 0; q < OPT / 4; q++) {
        float4 hv = hr[q];
        float ho[4] = {hv.x, hv.y, hv.z, hv.w};
#pragma unroll
        for (int a = 0; a < 4; a++)
#pragma unroll
          for (int t = 0; t < 4; t++)
            ac[a][q * 4 + t] = fmaf(pj[a], ho[t], ac[a][q * 4 + t]);
      }
    }
  }
  for (; n < len; n++) {
    float4 p = *(const float4*)&Pb[(size_t)(n0 + n) * Nnext];
    const float4* hr = (const float4*)&hs[n * COUT + o0];
    float pj[4] = {p.x, p.y, p.z, p.w};
#pragma unroll
    for (int q = 0; q < OPT / 4; q++) {
      float4 hv = hr[q];
      float ho[4] = {hv.x, hv.y, hv.z, hv.w};
#pragma unroll
      for (int a = 0; a < 4; a++)
#pragma unroll
        for (int t = 0; t < 4; t++)
          ac[a][q * 4 + t] = fmaf(pj[a], ho[t], ac[a][q * 4 + t]);
    }
  }
  float* pp = partial + ((size_t)c * Nnext + j0) * COUT + o0;
#pragma unroll
  for (int a = 0; a < 4; a++)
#pragma unroll
    for (int q = 0; q < OPT / 4; q++)
      *(float4*)(pp + (size_t)a * COUT + q * 4) =
          make_float4(ac[a][q * 4 + 0], ac[a][q * 4 + 1],
                      ac[a][q * 4 + 2], ac[a][q * 4 + 3]);
}

// ---------------- pool reduce ----------------
__global__ __launch_bounds__(256) void preduce_kernel(
    const float* __restrict__ partial, float* __restrict__ xnext,
    int NnCout, int chunks) {
  int i = blockIdx.x * 256 + threadIdx.x;
  if (i >= NnCout) return;
  float s = 0.0f;
  for (int c = 0; c < chunks; c++) s += partial[(size_t)c * NnCout + i];
  xnext[i] = s;
}

// ---------------- L5: epilogue + pool + final max, single block ----------------
// Nsrc=32, Nn=16, COUT=128, Cin=128, kchunks=16
__global__ __launch_bounds__(256) void poolmax_kernel(
    const float* __restrict__ P, const float* __restrict__ gpart,
    const float* __restrict__ deg, const float* __restrict__ x,
    const float* __restrict__ R, const float* __restrict__ bias,
    float* __restrict__ out) {
  __shared__ float hs[32 * 128];
  __shared__ float xn[16 * 128];
  const int NS = 32, NN = 16, C = 128, KC = 16, CIN = 128;
  size_t gstride = (size_t)NS * C;
  for (int t = threadIdx.x; t < NS * (C / 4); t += 256) {
    int n = t / (C / 4), o4 = t % (C / 4);
    const float* gp = &gpart[(size_t)n * C + o4 * 4];
    float4 s = make_float4(0.0f, 0.0f, 0.0f, 0.0f);
    for (int k = 0; k < KC; k++) {
      float4 v = *(const float4*)(gp + (size_t)k * gstride);
      s.x += v.x; s.y += v.y; s.z += v.z; s.w += v.w;
    }
    float invd = 1.0f / fmaxf(deg[n], 1.0f);
    float4 r = *(const float4*)&bias[o4 * 4];
    const float* xr = &x[(size_t)n * CIN];
    for (int i = 0; i < CIN; i++) {
      float xv = xr[i];
      float4 Rv = *(const float4*)&R[(size_t)i * C + o4 * 4];
      r.x = fmaf(xv, Rv.x, r.x); r.y = fmaf(xv, Rv.y, r.y);
      r.z = fmaf(xv, Rv.z, r.z); r.w = fmaf(xv, Rv.w, r.w);
    }
    float4 v;
    v.x = elu1(fmaf(s.x, invd, r.x));
    v.y = elu1(fmaf(s.y, invd, r.y));
    v.z = elu1(fmaf(s.z, invd, r.z));
    v.w = elu1(fmaf(s.w, invd, r.w));
    ((float4*)hs)[t] = v;
  }
  __syncthreads();
  int item = threadIdx.x;
  if (item < 64) {                       // (16/4) j-groups x (128/8) o-groups
    int j0 = (item & 3) << 2;
    int o0 = (item >> 2) << 3;
    float ac[4][8];
#pragma unroll
    for (int a = 0; a < 4; a++)
#pragma unroll
      for (int b = 0; b < 8; b++) ac[a][b] = 0.0f;
    for (int n = 0; n < NS; n++) {
      float4 p = *(const float4*)&P[n * NN + j0];
      const float4* hr = (const float4*)&hs[n * C + o0];
      float4 hA = hr[0], hB = hr[1];
      float pj[4] = {p.x, p.y, p.z, p.w};
      float ho[8] = {hA.x, hA.y, hA.z, hA.w, hB.x, hB.y, hB.z, hB.w};
#pragma unroll
      for (int a = 0; a < 4; a++)
#pragma unroll
        for (int b = 0; b < 8; b++) ac[a][b] = fmaf(pj[a], ho[b], ac[a][b]);
    }
#pragma unroll
    for (int a = 0; a < 4; a++)
#pragma unroll
      for (int b = 0; b < 8; b++) xn[(j0 + a) * C + o0 + b] = ac[a][b];
  }
  __syncthreads();
  if (threadIdx.x < C) {
    int o = threadIdx.x;
    float m = -3.0e38f;
    for (int n = 0; n < NN; n++) m = fmaxf(m, xn[n * C + o]);
    out[o] = m;
  }
}

extern "C" void kernel_launch(void* const* d_in, const int* in_sizes, int n_in,
                              void* d_out, int out_size, void* d_ws, size_t ws_size,
                              hipStream_t stream) {
  static const int NSh[7] = {20000, 5000, 1280, 320, 80, 32, 16};
  static const int ESh[6] = {320000, 80000, 20480, 5120, 1280, 512};
  static const int NFh[7] = {2, 16, 32, 64, 128, 128, 128};
  static const int cinSh[6]  = {1, 4, 5, 6, 7, 7};
  static const int KSt[6] = {256, 2016, 4000, 8000, 16000, 16000};
  static const int kchunksTab[6] = {4, 8, 16, 16, 16, 16};
  static const int ktilesTab[6]  = {2, 8, 8, 16, 32, 32};
  static const int poolChunksTab[5] = {160, 64, 16, 4, 1};
  // A region offsets (floats)
  static const size_t Aoff[6] = {0, 5120000, 15200000, 20320000, 22880000, 24160000};
  static const size_t degBase = 24672000;
  static const size_t degOff[6] = {0, 20000, 25000, 26280, 26600, 26680};
  const int ZTOT4 = 6174678;  // (24672000 + 26712) / 4

  const float* x0 = (const float*)d_in[0];
  const int* ei[6];
  const float* ea[6];
  for (int l = 0; l < 6; l++) {
    ei[l] = (const int*)d_in[1 + 2 * l];
    ea[l] = (const float*)d_in[2 + 2 * l];
  }
  const float* Pm[6];
  for (int l = 0; l < 6; l++) Pm[l] = (const float*)d_in[13 + l];
  const float* Wt[6];
  const float* Rt[6];
  const float* bt[6];
  for (int l = 0; l < 6; l++) {
    Wt[l] = (const float*)d_in[19 + 3 * l];
    Rt[l] = (const float*)d_in[20 + 3 * l];
    bt[l] = (const float*)d_in[21 + 3 * l];
  }

  float* ws = (float*)d_ws;
  float* gpart = ws + 24700000;  // max 1.31M
  float* ppart = ws + 26500000;  // max 12.8M (L0: 160 chunks x 80000)
  float* xA    = ws + 39400000;
  float* xB    = ws + 39600000;

  zero_kernel<<<2048, 256, 0, stream>>>((float4*)ws, ZTOT4);

  const float* cur = x0;
  for (int l = 0; l < 6; l++) {
    int N = NSh[l], Nn = NSh[l + 1], Cin = NFh[l], Cout = NFh[l + 1], E = ESh[l];
    int Kdim = NKER * Cin, KS = KSt[l];
    float* A = ws + Aoff[l];
    float* degL = ws + degBase + degOff[l];
    float* xnext = (l & 1) ? xB : xA;

    int sthreads = E << cinSh[l];
    scatter_kernel<<<(sthreads + 255) / 256, 256, 0, stream>>>(
        ei[l], ea[l], cur, A, degL, E, cinSh[l], KS);

    int kchunks = kchunksTab[l], ktiles = ktilesTab[l];
    switch (l) {
      case 0: {
        dim3 g((N + 127) / 128, kchunks);
        gemm3_kernel<128, 16, 128><<<g, 128, 0, stream>>>(A, Wt[l], gpart, N, Kdim, KS, ktiles);
        break;
      }
      case 1: {
        dim3 g((N + 127) / 128, kchunks);
        gemm3_kernel<128, 32, 256><<<g, 256, 0, stream>>>(A, Wt[l], gpart, N, Kdim, KS, ktiles);
        break;
      }
      case 2: {
        dim3 g((N + 63) / 64, kchunks);
        gemm3_kernel<64, 64, 256><<<g, 256, 0, stream>>>(A, Wt[l], gpart, N, Kdim, KS, ktiles);
        break;
      }
      default: {
        dim3 g((N + 31) / 32, kchunks);
        gemm3_kernel<32, 128, 256><<<g, 256, 0, stream>>>(A, Wt[l], gpart, N, Kdim, KS, ktiles);
        break;
      }
    }

    if (l == 5) {
      poolmax_kernel<<<1, 256, 0, stream>>>(Pm[5], gpart, degL, cur, Rt[5], bt[5],
                                            (float*)d_out);
      break;
    }

    int pc = poolChunksTab[l];
    int chunk = (N + pc - 1) / pc;
    size_t ldsB = (size_t)chunk * Cout * sizeof(float);
    float* pdst = (pc == 1) ? xnext : ppart;
    int items;
    switch (l) {
      case 0:  // Cout=16, OPT=16
        items = (Nn >> 2) * 1;
        pool6_kernel<16, 16><<<dim3((items + 255) / 256, pc), 256, ldsB, stream>>>(
            Pm[l], gpart, degL, cur, Rt[l], bt[l], pdst, N, Nn, Cin, kchunks, chunk, items);
        break;
      case 1:  // Cout=32, OPT=16
        items = (Nn >> 2) * 2;
        pool6_kernel<32, 16><<<dim3((items + 255) / 256, pc), 256, ldsB, stream>>>(
            Pm[l], gpart, degL, cur, Rt[l], bt[l], pdst, N, Nn, Cin, kchunks, chunk, items);
        break;
      case 2:  // Cout=64, OPT=8
        items = (Nn >> 2) * 8;
        pool6_kernel<64, 8><<<dim3((items + 255) / 256, pc), 256, ldsB, stream>>>(
            Pm[l], gpart, degL, cur, Rt[l], bt[l], pdst, N, Nn, Cin, kchunks, chunk, items);
        break;
      case 3:  // Cout=128, OPT=16
        items = (Nn >> 2) * 8;
        pool6_kernel<128, 16><<<dim3((items + 255) / 256, pc), 256, ldsB, stream>>>(
            Pm[l], gpart, degL, cur, Rt[l], bt[l], pdst, N, Nn, Cin, kchunks, chunk, items);
        break;
      default:  // l==4: Cout=128, OPT=8, pc=1 -> writes xnext directly
        items = (Nn >> 2) * 16;
        pool6_kernel<128, 8><<<dim3((items + 255) / 256, pc), 256, ldsB, stream>>>(
            Pm[l], gpart, degL, cur, Rt[l], bt[l], pdst, N, Nn, Cin, kchunks, chunk, items);
        break;
    }
    if (pc > 1) {
      int NnCout = Nn * Cout;
      preduce_kernel<<<(NnCout + 255) / 256, 256, 0, stream>>>(ppart, xnext, NnCout, pc);
    }

    cur = xnext;
  }
}

// Round 7
// 1053.739 us; speedup vs baseline: 1.2751x; 1.2751x over previous
//
#include <hip/hip_runtime.h>
#include <math.h>

#define NKER 125

// ---------------- scatter: A[dst*KS + kidx*Cin + i] += wprod * x[src,ci]; deg[dst] += 1 ----------------
__global__ __launch_bounds__(256) void scatter_kernel(
    const int* __restrict__ ei, const float* __restrict__ ea,
    const float* __restrict__ x, float* __restrict__ A,
    float* __restrict__ deg, int E, int cinShift, int KS) {
  int tid = blockIdx.x * 256 + threadIdx.x;
  int Cin = 1 << cinShift;
  if (tid >= (E << cinShift)) return;
  int e = tid >> cinShift;
  int i = tid & (Cin - 1);
  int src = ei[e];
  int dst = ei[E + e];
  float xv = x[((size_t)src << cinShift) + i];
  float w[3][2];
  int k0[3];
#pragma unroll
  for (int d = 0; d < 3; d++) {
    float p = ea[e * 3 + d] * 4.0f;
    float kf = fminf(fmaxf(floorf(p), 0.0f), 3.0f);
    float f = p - kf;
    k0[d] = (int)kf;
    w[d][0] = 1.0f - f;
    w[d][1] = f;
  }
  float* Arow = A + (size_t)dst * KS + i;
#pragma unroll
  for (int c = 0; c < 8; c++) {
    int b0 = c & 1, b1 = (c >> 1) & 1, b2 = (c >> 2) & 1;
    float wp = w[0][b0] * w[1][b1] * w[2][b2];
    int kidx = (k0[0] + b0) + 5 * (k0[1] + b1) + 25 * (k0[2] + b2);
    atomicAdd(&Arow[kidx << cinShift], wp * xv);
  }
  if (i == 0) atomicAdd(&deg[dst], 1.0f);
}

// ---------------- GEMM v3: register-tiled 4x4, float4 staging, partials out (no atomics) ----------------
template <int BM, int COUT, int NT>
__global__ __launch_bounds__(NT) void gemm3_kernel(
    const float* __restrict__ A, const float* __restrict__ W,
    float* __restrict__ gpart, int M, int Kdim, int KS, int ktiles) {
  const int BK = 32;
  __shared__ float At[BK][BM + 4];
  __shared__ float Wl[BK][COUT];
  const int TC = COUT / 4;
  int tid = threadIdx.x;
  int tc = tid % TC;
  int tr = tid / TC;
  int m0 = blockIdx.x * BM;
  int kbeg = blockIdx.y * ktiles * BK;
  int kend = min(KS, kbeg + ktiles * BK);
  float ar[4][4];
#pragma unroll
  for (int i = 0; i < 4; i++)
#pragma unroll
    for (int j = 0; j < 4; j++) ar[i][j] = 0.0f;

  for (int k0 = kbeg; k0 < kend; k0 += BK) {
    for (int t = tid; t < BM * (BK / 4); t += NT) {
      int c4 = t % (BK / 4), r = t / (BK / 4);
      int m = m0 + r;
      float4 v = make_float4(0.0f, 0.0f, 0.0f, 0.0f);
      if (m < M) v = *(const float4*)&A[(size_t)m * KS + k0 + c4 * 4];
      At[c4 * 4 + 0][r] = v.x; At[c4 * 4 + 1][r] = v.y;
      At[c4 * 4 + 2][r] = v.z; At[c4 * 4 + 3][r] = v.w;
    }
    int kleft = Kdim - k0;
    if (kleft >= BK) {
      for (int t = tid; t < BK * COUT / 4; t += NT)
        ((float4*)&Wl[0][0])[t] = ((const float4*)&W[(size_t)k0 * COUT])[t];
    } else {
      for (int t = tid; t < BK * COUT; t += NT) {
        int kk = t / COUT, o = t % COUT;
        Wl[kk][o] = (kk < kleft) ? W[(size_t)(k0 + kk) * COUT + o] : 0.0f;
      }
    }
    __syncthreads();
#pragma unroll
    for (int kk = 0; kk < BK; kk++) {
      float4 a = *(const float4*)&At[kk][tr * 4];
      float4 w = *(const float4*)&Wl[kk][tc * 4];
      float av[4] = {a.x, a.y, a.z, a.w};
      float wv[4] = {w.x, w.y, w.z, w.w};
#pragma unroll
      for (int i = 0; i < 4; i++)
#pragma unroll
        for (int j = 0; j < 4; j++)
          ar[i][j] = fmaf(av[i], wv[j], ar[i][j]);
    }
    __syncthreads();
  }
  float* gp = gpart + ((size_t)blockIdx.y * M) * COUT + tc * 4;
#pragma unroll
  for (int i = 0; i < 4; i++) {
    int m = m0 + tr * 4 + i;
    if (m < M)
      *(float4*)(gp + (size_t)m * COUT) =
          make_float4(ar[i][0], ar[i][1], ar[i][2], ar[i][3]);
  }
}

// ---------------- epilogue: h = elu(sum_c gpart[c]/max(deg,1) + x@R + b) ----------------
__global__ __launch_bounds__(256) void epilogue_kernel(
    const float* __restrict__ gpart, const float* __restrict__ deg,
    const float* __restrict__ x, const float* __restrict__ R,
    const float* __restrict__ b, float* __restrict__ h,
    int N, int Cin, int coutShift, int kchunks) {
  int tid = blockIdx.x * 256 + threadIdx.x;
  int Cout = 1 << coutShift;
  if (tid >= (N << coutShift)) return;
  int n = tid >> coutShift;
  int o = tid & (Cout - 1);
  size_t stride = (size_t)N << coutShift;
  float s = 0.0f;
  for (int c = 0; c < kchunks; c++) s += gpart[(size_t)c * stride + tid];
  s /= fmaxf(deg[n], 1.0f);
  float r = b[o];
  const float* xr = &x[n * Cin];
  for (int i = 0; i < Cin; i++) r = fmaf(xr[i], R[i * Cout + o], r);
  float v = s + r;
  h[tid] = v > 0.0f ? v : expm1f(v);
}

// ---------------- pool v5b: named-float4 accumulators (spill-proof), h tile in LDS ----------------
#define FMA4(c, pj, h) \
  c.x = fmaf(pj, h.x, c.x); c.y = fmaf(pj, h.y, c.y); \
  c.z = fmaf(pj, h.z, c.z); c.w = fmaf(pj, h.w, c.w);

template <int COUT, int OPT>
__global__ __launch_bounds__(256) void pool5b_kernel(
    const float* __restrict__ P, const float* __restrict__ h,
    float* __restrict__ partial, int Nsrc, int Nnext, int chunk, int items) {
  extern __shared__ float hs[];
  int c = blockIdx.y;
  int n0 = c * chunk;
  int n1 = min(Nsrc, n0 + chunk);
  int len = n1 - n0;
  for (int t = threadIdx.x; t < len * (COUT / 4); t += 256)
    ((float4*)hs)[t] = ((const float4*)&h[(size_t)n0 * COUT])[t];
  __syncthreads();
  int item = blockIdx.x * 256 + threadIdx.x;
  if (item >= items) return;
  int nj4 = Nnext >> 2;
  int j0 = (item % nj4) << 2;
  int o0 = (item / nj4) * OPT;
  const float4 z = make_float4(0.0f, 0.0f, 0.0f, 0.0f);
  float4 c00 = z, c01 = z, c02 = z, c03 = z;
  float4 c10 = z, c11 = z, c12 = z, c13 = z;
  float4 c20 = z, c21 = z, c22 = z, c23 = z;
  float4 c30 = z, c31 = z, c32 = z, c33 = z;
  const float* Pb = P + j0;

#define USTEP(pv, nn)                                                    \
  {                                                                      \
    const float4* hr = (const float4*)&hs[(nn) * COUT + o0];             \
    float4 h0 = hr[0], h1 = hr[1];                                       \
    FMA4(c00, pv.x, h0) FMA4(c01, pv.x, h1)                              \
    FMA4(c10, pv.y, h0) FMA4(c11, pv.y, h1)                              \
    FMA4(c20, pv.z, h0) FMA4(c21, pv.z, h1)                              \
    FMA4(c30, pv.w, h0) FMA4(c31, pv.w, h1)                              \
    if constexpr (OPT == 16) {                                           \
      float4 h2 = hr[2], h3 = hr[3];                                     \
      FMA4(c02, pv.x, h2) FMA4(c03, pv.x, h3)                            \
      FMA4(c12, pv.y, h2) FMA4(c13, pv.y, h3)                            \
      FMA4(c22, pv.z, h2) FMA4(c23, pv.z, h3)                            \
      FMA4(c32, pv.w, h2) FMA4(c33, pv.w, h3)                            \
    }                                                                    \
  }

  int n = 0;
  for (; n + 4 <= len; n += 4) {
    float4 pv0 = *(const float4*)&Pb[(size_t)(n0 + n + 0) * Nnext];
    float4 pv1 = *(const float4*)&Pb[(size_t)(n0 + n + 1) * Nnext];
    float4 pv2 = *(const float4*)&Pb[(size_t)(n0 + n + 2) * Nnext];
    float4 pv3 = *(const float4*)&Pb[(size_t)(n0 + n + 3) * Nnext];
    USTEP(pv0, n + 0)
    USTEP(pv1, n + 1)
    USTEP(pv2, n + 2)
    USTEP(pv3, n + 3)
  }
  for (; n < len; n++) {
    float4 pv = *(const float4*)&Pb[(size_t)(n0 + n) * Nnext];
    USTEP(pv, n)
  }
#undef USTEP

  float* pp = partial + ((size_t)c * Nnext + j0) * COUT + o0;
  *(float4*)(pp + 0 * COUT + 0) = c00;
  *(float4*)(pp + 0 * COUT + 4) = c01;
  *(float4*)(pp + 1 * COUT + 0) = c10;
  *(float4*)(pp + 1 * COUT + 4) = c11;
  *(float4*)(pp + 2 * COUT + 0) = c20;
  *(float4*)(pp + 2 * COUT + 4) = c21;
  *(float4*)(pp + 3 * COUT + 0) = c30;
  *(float4*)(pp + 3 * COUT + 4) = c31;
  if constexpr (OPT == 16) {
    *(float4*)(pp + 0 * COUT + 8)  = c02;
    *(float4*)(pp + 0 * COUT + 12) = c03;
    *(float4*)(pp + 1 * COUT + 8)  = c12;
    *(float4*)(pp + 1 * COUT + 12) = c13;
    *(float4*)(pp + 2 * COUT + 8)  = c22;
    *(float4*)(pp + 2 * COUT + 12) = c23;
    *(float4*)(pp + 3 * COUT + 8)  = c32;
    *(float4*)(pp + 3 * COUT + 12) = c33;
  }
}

// ---------------- pool reduce: one float per thread, coalesced, no atomics ----------------
__global__ __launch_bounds__(256) void preduce_kernel(
    const float* __restrict__ partial, float* __restrict__ xnext,
    int NnCout, int chunks) {
  int i = blockIdx.x * 256 + threadIdx.x;
  if (i >= NnCout) return;
  float s = 0.0f;
  for (int c = 0; c < chunks; c++) s += partial[(size_t)c * NnCout + i];
  xnext[i] = s;
}

// ---------------- final max over 16 nodes -> out[128] ----------------
__global__ __launch_bounds__(128) void max_kernel(const float* __restrict__ x6,
                                                  float* __restrict__ out) {
  int o = threadIdx.x;
  float m = -3.0e38f;
  for (int n = 0; n < 16; n++) m = fmaxf(m, x6[n * 128 + o]);
  out[o] = m;
}

extern "C" void kernel_launch(void* const* d_in, const int* in_sizes, int n_in,
                              void* d_out, int out_size, void* d_ws, size_t ws_size,
                              hipStream_t stream) {
  static const int NSh[7] = {20000, 5000, 1280, 320, 80, 32, 16};
  static const int ESh[6] = {320000, 80000, 20480, 5120, 1280, 512};
  static const int NFh[7] = {2, 16, 32, 64, 128, 128, 128};
  static const int cinSh[6]  = {1, 4, 5, 6, 7, 7};
  static const int coutSh[6] = {4, 5, 6, 7, 7, 7};
  static const int KSt[6] = {256, 2016, 4000, 8000, 16000, 16000};  // K padded to %32
  static const int kchunksTab[6] = {4, 8, 16, 32, 64, 128};
  static const int ktilesTab[6]  = {2, 8, 8, 8, 8, 4};   // kchunks*ktiles*32 >= KS
  static const int poolChunksTab[6] = {120, 64, 16, 8, 4, 2};

  const float* x0 = (const float*)d_in[0];
  const int* ei[6];
  const float* ea[6];
  for (int l = 0; l < 6; l++) {
    ei[l] = (const int*)d_in[1 + 2 * l];
    ea[l] = (const float*)d_in[2 + 2 * l];
  }
  const float* Pm[6];
  for (int l = 0; l < 6; l++) Pm[l] = (const float*)d_in[13 + l];
  const float* Wt[6];
  const float* Rt[6];
  const float* bt[6];
  for (int l = 0; l < 6; l++) {
    Wt[l] = (const float*)d_in[19 + 3 * l];
    Rt[l] = (const float*)d_in[20 + 3 * l];
    bt[l] = (const float*)d_in[21 + 3 * l];
  }

  // workspace layout (floats); ws ~1.6GB, we use ~87MB
  float* ws = (float*)d_ws;
  float* A     = ws;                  // max N*KS + N (deg) = 10.085M floats (layer 1)
  float* gpart = ws + 10150000;       // max kchunks*N*Cout = 1.31M
  float* hbuf  = ws + 11500000;       // max 320000
  float* ppart = ws + 11900000;       // max pc*Nn*Cout = 9.6M
  float* xA    = ws + 21600000;       // 80000
  float* xB    = ws + 21700000;       // 80000

  const float* cur = x0;
  for (int l = 0; l < 6; l++) {
    int N = NSh[l], Nn = NSh[l + 1], Cin = NFh[l], Cout = NFh[l + 1], E = ESh[l];
    int Kdim = NKER * Cin, KS = KSt[l];
    float* xnext = (l & 1) ? xB : xA;
    float* degL = A + (size_t)N * KS;   // deg contiguous with A -> one memset

    hipMemsetAsync(A, 0, ((size_t)N * KS + N) * sizeof(float), stream);

    int sthreads = E << cinSh[l];
    scatter_kernel<<<(sthreads + 255) / 256, 256, 0, stream>>>(
        ei[l], ea[l], cur, A, degL, E, cinSh[l], KS);

    int kchunks = kchunksTab[l], ktiles = ktilesTab[l];
    switch (l) {
      case 0: {
        dim3 g((N + 127) / 128, kchunks);
        gemm3_kernel<128, 16, 128><<<g, 128, 0, stream>>>(A, Wt[l], gpart, N, Kdim, KS, ktiles);
        break;
      }
      case 1: {
        dim3 g((N + 127) / 128, kchunks);
        gemm3_kernel<128, 32, 256><<<g, 256, 0, stream>>>(A, Wt[l], gpart, N, Kdim, KS, ktiles);
        break;
      }
      case 2: {
        dim3 g((N + 63) / 64, kchunks);
        gemm3_kernel<64, 64, 256><<<g, 256, 0, stream>>>(A, Wt[l], gpart, N, Kdim, KS, ktiles);
        break;
      }
      default: {
        dim3 g((N + 31) / 32, kchunks);
        gemm3_kernel<32, 128, 256><<<g, 256, 0, stream>>>(A, Wt[l], gpart, N, Kdim, KS, ktiles);
        break;
      }
    }

    int ethreads = N << coutSh[l];
    epilogue_kernel<<<(ethreads + 255) / 256, 256, 0, stream>>>(
        gpart, degL, cur, Rt[l], bt[l], hbuf, N, Cin, coutSh[l], kchunks);

    int pc = poolChunksTab[l];
    int chunk = (N + pc - 1) / pc;
    size_t ldsB = (size_t)chunk * Cout * sizeof(float);
    int items, gx;
    switch (Cout) {
      case 16: {
        items = (Nn >> 2) * 1;
        gx = (items + 255) / 256;
        // measurement rider: L0 pool dispatched 3x total (idempotent pure-write);
        // delta_total/2 = true per-dispatch cost of pool0
        pool5b_kernel<16, 16><<<dim3(gx, pc), 256, ldsB, stream>>>(Pm[l], hbuf, ppart, N, Nn, chunk, items);
        pool5b_kernel<16, 16><<<dim3(gx, pc), 256, ldsB, stream>>>(Pm[l], hbuf, ppart, N, Nn, chunk, items);
        pool5b_kernel<16, 16><<<dim3(gx, pc), 256, ldsB, stream>>>(Pm[l], hbuf, ppart, N, Nn, chunk, items);
        break;
      }
      case 32:
        items = (Nn >> 2) * 2;
        gx = (items + 255) / 256;
        pool5b_kernel<32, 16><<<dim3(gx, pc), 256, ldsB, stream>>>(Pm[l], hbuf, ppart, N, Nn, chunk, items);
        break;
      case 64:
        items = (Nn >> 2) * 8;
        gx = (items + 255) / 256;
        pool5b_kernel<64, 8><<<dim3(gx, pc), 256, ldsB, stream>>>(Pm[l], hbuf, ppart, N, Nn, chunk, items);
        break;
      default:
        items = (Nn >> 2) * 16;
        gx = (items + 255) / 256;
        pool5b_kernel<128, 8><<<dim3(gx, pc), 256, ldsB, stream>>>(Pm[l], hbuf, ppart, N, Nn, chunk, items);
        break;
    }
    int NnCout = Nn << coutSh[l];
    preduce_kernel<<<(NnCout + 255) / 256, 256, 0, stream>>>(ppart, xnext, NnCout, pc);

    cur = xnext;
  }

  max_kernel<<<1, 128, 0, stream>>>(cur, (float*)d_out);
}